// Round 6
// baseline (111.436 us; speedup 1.0000x reference)
//
#include <hip/hip_runtime.h>
#include <hip/hip_bf16.h>

// MEASUREMENT ROUND: kernels identical to R4. Launcher replays normalize x3,
// maxsim x5 (all idempotent) to solve the time split exactly:
//   R4:   N + M = 29.8 us
//   here: D = 3N + 5M  =>  M = (D - 89.4)/2
//
// out[a,b] = sum_i max_j_in_image_b <pano_n[a,i,:], sat_n[b,j,:]>
// d_in[0] sat  [256,64,128] fp32 -> 16384 rows (j, GEMM M / C-rows, streamed via LDS)
// d_in[1] pano [ 64,64,128] fp32 ->  4096 rows (i, GEMM N / C-cols, held in VGPRs)
// out [64,256] fp32

typedef __bf16 bf16x8 __attribute__((ext_vector_type(8)));
typedef float  f32x16 __attribute__((ext_vector_type(16)));
typedef unsigned int u32;

__device__ __forceinline__ void gload16(const void* g, void* l) {
    __builtin_amdgcn_global_load_lds((const __attribute__((address_space(1))) u32*)g,
                                     (__attribute__((address_space(3))) u32*)l, 16, 0, 0);
}

__device__ __forceinline__ unsigned short f2bf_rne(float x) {
    u32 u = __builtin_bit_cast(u32, x);
    return (unsigned short)((u + 0x7FFFu + ((u >> 16) & 1u)) >> 16);
}

// 32 lanes per row of 128 floats: L2-normalize, emit bf16. Handles both tensors.
__global__ __launch_bounds__(256) void normalize_all(
        const float* __restrict__ sat, const float* __restrict__ pano,
        unsigned short* __restrict__ satN, unsigned short* __restrict__ panoN) {
    int row  = blockIdx.x * 8 + (threadIdx.x >> 5);
    int lane = threadIdx.x & 31;
    const float* src;
    unsigned short* dst;
    if (row < 16384) { src = sat  + (size_t)row * 128;           dst = satN  + (size_t)row * 128; }
    else             { src = pano + (size_t)(row - 16384) * 128; dst = panoN + (size_t)(row - 16384) * 128; }
    const float4 v = *reinterpret_cast<const float4*>(src + lane * 4);
    float ss = v.x * v.x + v.y * v.y + v.z * v.z + v.w * v.w;
    #pragma unroll
    for (int m = 16; m >= 1; m >>= 1) ss += __shfl_xor(ss, m);
    float sc = 1.0f / fmaxf(sqrtf(ss), 1e-12f);
    ushort4 o;
    o.x = f2bf_rne(v.x * sc); o.y = f2bf_rne(v.y * sc);
    o.z = f2bf_rne(v.z * sc); o.w = f2bf_rne(v.w * sc);
    *reinterpret_cast<ushort4*>(dst + lane * 4) = o;
}

__global__ __launch_bounds__(256, 2) void maxsim_kernel(
        const unsigned short* __restrict__ satN,
        const unsigned short* __restrict__ panoN,
        float* __restrict__ out) {
    __shared__ unsigned short Slds[4][128 * 64];   // 4 x 16 KB ring of sat K-halves

    const int tid  = threadIdx.x;
    const int wid  = tid >> 6;
    const int lane = tid & 63;
    const int rl   = lane & 31;
    const int hi   = lane >> 5;

    const int bid = blockIdx.x;
    const int swz = (bid & 7) * 64 + (bid >> 3);   // XCD-contiguous (512 % 8 == 0)
    const int jg  = swz >> 5;                      // 0..15: sat j-group (8 tiles of 128)
    const int it  = swz & 31;                      // 0..31: pano panel (128 i-cols)

    const int wm = wid >> 1;                       // 0..1: j 64-half within tile
    const int wn = wid & 1;                        // 0..1: i 64-half (one a-image)

    // ---- B (pano) fragments: 64 i-cols x K=128, 64 VGPR, loaded once ----
    bf16x8 bfr[2][8];
    {
        const unsigned short* pb =
            panoN + ((size_t)(it * 128 + wn * 64 + rl)) * 128 + hi * 8;
        #pragma unroll
        for (int n = 0; n < 2; ++n)
            #pragma unroll
            for (int ks = 0; ks < 8; ++ks)
                bfr[n][ks] = *reinterpret_cast<const bf16x8*>(pb + (size_t)n * 32 * 128 + ks * 16);
    }

#define STAGE(h_) do {                                                          \
    const char* gb_ = (const char*)satN                                         \
        + ((size_t)(jg * 1024 + ((h_) >> 1) * 128)) * 256 + ((h_) & 1) * 128;   \
    char* lb_ = (char*)&Slds[(h_) & 3][0];                                      \
    _Pragma("unroll")                                                           \
    for (int i_ = 0; i_ < 4; ++i_) {                                            \
        int P_ = (wid * 4 + i_) * 1024 + lane * 16;                             \
        int r_ = P_ >> 7;                                                       \
        int g_ = ((P_ >> 4) & 7) ^ (r_ & 7);                                    \
        gload16(gb_ + (size_t)r_ * 256 + g_ * 16, lb_ + P_);                    \
    } } while (0)

#define COMPUTE(h_, koff_) do {                                                 \
    const char* sb_ = (const char*)&Slds[(h_) & 3][0];                          \
    __builtin_amdgcn_s_setprio(1);                                              \
    _Pragma("unroll")                                                           \
    for (int ks = 0; ks < 4; ++ks) {                                            \
        bf16x8 a_[2];                                                           \
        _Pragma("unroll")                                                       \
        for (int m = 0; m < 2; ++m) {                                           \
            int row = wm * 64 + m * 32 + rl;                                    \
            a_[m] = *(const bf16x8*)(sb_ + row * 128 + ((((ks << 1) | hi) ^ (row & 7)) << 4)); \
        }                                                                       \
        _Pragma("unroll")                                                       \
        for (int m = 0; m < 2; ++m)                                             \
            _Pragma("unroll")                                                   \
            for (int n = 0; n < 2; ++n)                                         \
                acc[m][n] = __builtin_amdgcn_mfma_f32_32x32x16_bf16(            \
                    a_[m], bfr[n][(koff_) + ks], acc[m][n], 0, 0, 0);           \
    }                                                                           \
    __builtin_amdgcn_s_setprio(0);                                              \
} while (0)

#define SYNC(N_) do {                                                           \
    asm volatile("s_waitcnt vmcnt(" #N_ ")" ::: "memory");                      \
    __builtin_amdgcn_s_barrier();                                               \
    __builtin_amdgcn_sched_barrier(0);                                          \
} while (0)

#define EPILOGUE(t_) do {                                                       \
    float v0 = acc[0][0][0], v1 = acc[0][1][0];                                 \
    _Pragma("unroll")                                                           \
    for (int m = 0; m < 2; ++m)                                                 \
        _Pragma("unroll")                                                       \
        for (int q = 0; q < 16; ++q) {                                          \
            if (m == 0 && q == 0) continue;                                     \
            v0 = fmaxf(v0, acc[m][0][q]);                                       \
            v1 = fmaxf(v1, acc[m][1][q]);                                       \
        }                                                                       \
    v0 = fmaxf(v0, __shfl_xor(v0, 32));                                         \
    v1 = fmaxf(v1, __shfl_xor(v1, 32));                                         \
    float s_ = v0 + v1;                                                         \
    _Pragma("unroll")                                                           \
    for (int d_ = 1; d_ <= 16; d_ <<= 1) s_ += __shfl_xor(s_, d_);              \
    if (lane == 0) out[(it * 2 + wn) * 256 + (jg * 16 + (t_) * 2 + wm)] = s_;   \
    _Pragma("unroll")                                                           \
    for (int m = 0; m < 2; ++m)                                                 \
        _Pragma("unroll")                                                       \
        for (int n = 0; n < 2; ++n)                                             \
            _Pragma("unroll")                                                   \
            for (int q = 0; q < 16; ++q) acc[m][n][q] = 0.f;                    \
} while (0)

    STAGE(0); STAGE(1); STAGE(2);          // prefetch depth 3 (12 loads in flight)

    f32x16 acc[2][2];
    #pragma unroll
    for (int m = 0; m < 2; ++m)
        #pragma unroll
        for (int n = 0; n < 2; ++n)
            #pragma unroll
            for (int q = 0; q < 16; ++q) acc[m][n][q] = 0.f;

    #pragma unroll 1
    for (int t = 0; t < 7; ++t) {
        const int h0 = 2 * t;
        SYNC(8);
        STAGE(h0 + 3);
        __builtin_amdgcn_sched_barrier(0);
        COMPUTE(h0, 0);

        SYNC(8);
        if (t < 6) STAGE(h0 + 4);
        __builtin_amdgcn_sched_barrier(0);
        COMPUTE(h0 + 1, 4);

        EPILOGUE(t);
    }
    SYNC(4);
    COMPUTE(14, 0);
    SYNC(0);
    COMPUTE(15, 4);
    EPILOGUE(7);

#undef STAGE
#undef COMPUTE
#undef SYNC
#undef EPILOGUE
}

extern "C" void kernel_launch(void* const* d_in, const int* in_sizes, int n_in,
                              void* d_out, int out_size, void* d_ws, size_t ws_size,
                              hipStream_t stream) {
    const float* sat  = (const float*)d_in[0];   // [16384,128]
    const float* pano = (const float*)d_in[1];   // [ 4096,128]
    float* out = (float*)d_out;                  // [64,256]

    unsigned short* panoN = (unsigned short*)d_ws;        // 4096*128 bf16
    unsigned short* satN  = panoN + (size_t)4096 * 128;   // 16384*128 bf16

    // normalize x3 (idempotent), maxsim x5 (idempotent): D = 3N + 5M
    for (int r = 0; r < 3; ++r)
        normalize_all<<<2560, 256, 0, stream>>>(sat, pano, satN, panoN);
    for (int r = 0; r < 5; ++r)
        maxsim_kernel<<<512, 256, 0, stream>>>(satN, panoN, out);
}

// Round 8
// 52.855 us; speedup vs baseline: 2.1083x; 2.1083x over previous
//
#include <hip/hip_runtime.h>
#include <hip/hip_bf16.h>

// Fully fused single kernel, NO cross-block dependencies, d_ws unused.
// Each block normalizes the pano rows it holds in registers and the sat tiles
// it streams (redundantly across blocks; inputs are L2-resident).
// out[a,b] = sum_i max_j_in_image_b <pano_n[a,i,:], sat_n[b,j,:]>
// d_in[0] sat  [256,64,128] fp32 -> 16384 rows (j, GEMM M / C-rows, LDS-streamed)
// d_in[1] pano [ 64,64,128] fp32 ->  4096 rows (i, GEMM N / C-cols, in VGPRs)
// out [64,256] fp32

typedef __bf16 bf16x8 __attribute__((ext_vector_type(8)));
typedef float  f32x16 __attribute__((ext_vector_type(16)));
typedef unsigned int u32;
typedef u32 u32x4 __attribute__((ext_vector_type(4)));

__device__ __forceinline__ u32 pkbf16(float a, float b) {
    u32 r;
    asm("v_cvt_pk_bf16_f32 %0, %1, %2" : "=v"(r) : "v"(a), "v"(b));
    return r;   // lo=bf16(a), hi=bf16(b)
}

// 512 blocks x 256 threads (4 waves: wm x wn), 2 blocks/CU (64 KB LDS).
// Block = (jg: 8 sat tiles of 128 j-rows) x (it: 128 pano i-cols).
__global__ __launch_bounds__(256, 2) void fused_maxsim(
        const float* __restrict__ satF, const float* __restrict__ panoF,
        float* __restrict__ out) {
    __shared__ unsigned char Slds[2][32768];   // 2 tile bufs: [half(16KB)][row(128B)][slot(16B)]

    const int tid  = threadIdx.x;
    const int wid  = tid >> 6;
    const int lane = tid & 63;
    const int rl   = lane & 31;
    const int hi   = lane >> 5;
    const int rl16 = lane & 15;
    const int q4   = lane >> 4;                // 0..3 col-quarter for staging

    const int bid = blockIdx.x;
    const int swz = (bid & 7) * 64 + (bid >> 3);   // XCD-contiguous (512 % 8 == 0)
    const int jg  = swz >> 5;                      // 0..15
    const int it  = swz & 31;                      // 0..31
    const int wm  = wid >> 1;                      // 0..1: j 64-half of tile
    const int wn  = wid & 1;                       // 0..1: i 64-half (one a-image)

    // ---- pano: load fp32, normalize in-wave, pack to B fragments (64 VGPR) ----
    // B-frag: lane holds col(i-row)=wn*64+n*32+rl, k = ks*16 + hi*8 + 0..7
    bf16x8 bfr[2][8];
    #pragma unroll
    for (int n = 0; n < 2; ++n) {
        const float* pr = panoF + (size_t)(it * 128 + wn * 64 + n * 32 + rl) * 128 + hi * 8;
        float4 f[16];
        #pragma unroll
        for (int ks = 0; ks < 8; ++ks) {
            f[2*ks]   = *(const float4*)(pr + ks * 16);
            f[2*ks+1] = *(const float4*)(pr + ks * 16 + 4);
        }
        float ss = 0.f;
        #pragma unroll
        for (int i = 0; i < 16; ++i)
            ss += f[i].x*f[i].x + f[i].y*f[i].y + f[i].z*f[i].z + f[i].w*f[i].w;
        ss += __shfl_xor(ss, 32);              // hi=0/1 lanes hold complementary cols
        float sc = 1.0f / fmaxf(sqrtf(ss), 1e-12f);
        #pragma unroll
        for (int ks = 0; ks < 8; ++ks) {
            u32x4 w;
            w[0] = pkbf16(f[2*ks].x*sc,   f[2*ks].y*sc);
            w[1] = pkbf16(f[2*ks].z*sc,   f[2*ks].w*sc);
            w[2] = pkbf16(f[2*ks+1].x*sc, f[2*ks+1].y*sc);
            w[3] = pkbf16(f[2*ks+1].z*sc, f[2*ks+1].w*sc);
            bfr[n][ks] = __builtin_bit_cast(bf16x8, w);
        }
    }

// load both 64-row passes of sat tile t_ (4 lanes/row, 32 fp32 each)
#define SATLOAD(t_, fA_, fB_) do {                                              \
    const float* s0_ = satF + (size_t)(jg*1024 + (t_)*128 + wid*16 + rl16) * 128 + q4*32; \
    const float* s1_ = s0_ + 64 * 128;                                          \
    _Pragma("unroll") for (int i = 0; i < 8; ++i) fA_[i] = *(const float4*)(s0_ + i*4); \
    _Pragma("unroll") for (int i = 0; i < 8; ++i) fB_[i] = *(const float4*)(s1_ + i*4); \
} while (0)

// normalize 32 floats of row R_ and ds_write 4x b128 into buf b_ (swizzled)
#define SATNORM(f_, R_, b_) do {                                                \
    float ss_ = 0.f;                                                            \
    _Pragma("unroll") for (int i = 0; i < 8; ++i)                               \
        ss_ += f_[i].x*f_[i].x + f_[i].y*f_[i].y + f_[i].z*f_[i].z + f_[i].w*f_[i].w; \
    ss_ += __shfl_xor(ss_, 16); ss_ += __shfl_xor(ss_, 32);                     \
    float sc_ = 1.0f / fmaxf(sqrtf(ss_), 1e-12f);                               \
    char* lb_ = (char*)&Slds[b_][0];                                            \
    _Pragma("unroll") for (int j = 0; j < 4; ++j) {                             \
        int cg_ = q4*4 + j, h_ = cg_ >> 3, c_ = cg_ & 7;                        \
        u32x4 w_;                                                               \
        w_[0] = pkbf16(f_[2*j].x*sc_,   f_[2*j].y*sc_);                         \
        w_[1] = pkbf16(f_[2*j].z*sc_,   f_[2*j].w*sc_);                         \
        w_[2] = pkbf16(f_[2*j+1].x*sc_, f_[2*j+1].y*sc_);                       \
        w_[3] = pkbf16(f_[2*j+1].z*sc_, f_[2*j+1].w*sc_);                       \
        *(u32x4*)(lb_ + h_*16384 + (R_)*128 + ((c_ ^ ((R_) & 7)) << 4)) = w_;   \
    }                                                                           \
} while (0)

// MFMA over K-half h_ of buf b_: A row=wm*64+m*32+rl, k-chunk (ks<<1|hi)
#define COMPUTE(b_, h_, koff_) do {                                             \
    const char* sb_ = (const char*)&Slds[b_][0] + (h_) * 16384;                 \
    __builtin_amdgcn_s_setprio(1);                                              \
    _Pragma("unroll")                                                           \
    for (int ks = 0; ks < 4; ++ks) {                                            \
        bf16x8 a_[2];                                                           \
        _Pragma("unroll")                                                       \
        for (int m = 0; m < 2; ++m) {                                           \
            int row = wm*64 + m*32 + rl;                                        \
            a_[m] = *(const bf16x8*)(sb_ + row*128 + ((((ks<<1)|hi) ^ (row & 7)) << 4)); \
        }                                                                       \
        _Pragma("unroll")                                                       \
        for (int m = 0; m < 2; ++m)                                             \
            _Pragma("unroll")                                                   \
            for (int n = 0; n < 2; ++n)                                         \
                acc[m][n] = __builtin_amdgcn_mfma_f32_32x32x16_bf16(            \
                    a_[m], bfr[n][(koff_)+ks], acc[m][n], 0, 0, 0);             \
    }                                                                           \
    __builtin_amdgcn_s_setprio(0);                                              \
} while (0)

#define PUBLISH() do {                                                          \
    asm volatile("s_waitcnt lgkmcnt(0)" ::: "memory");                          \
    __builtin_amdgcn_s_barrier();                                               \
    __builtin_amdgcn_sched_barrier(0);                                          \
} while (0)

// epilogue: max_j within-lane (+hi-swap), sum_i butterfly; C 32x32 layout:
// row=(q&3)+8*(q>>2)+4*hi, col=lane&31
#define EPILOGUE(t_) do {                                                       \
    float v0 = acc[0][0][0], v1 = acc[0][1][0];                                 \
    _Pragma("unroll")                                                           \
    for (int m = 0; m < 2; ++m)                                                 \
        _Pragma("unroll")                                                       \
        for (int q = 0; q < 16; ++q) {                                          \
            if (m == 0 && q == 0) continue;                                     \
            v0 = fmaxf(v0, acc[m][0][q]);                                       \
            v1 = fmaxf(v1, acc[m][1][q]);                                       \
        }                                                                       \
    v0 = fmaxf(v0, __shfl_xor(v0, 32));                                         \
    v1 = fmaxf(v1, __shfl_xor(v1, 32));                                         \
    float s_ = v0 + v1;                                                         \
    _Pragma("unroll")                                                           \
    for (int d_ = 1; d_ <= 16; d_ <<= 1) s_ += __shfl_xor(s_, d_);              \
    if (lane == 0) out[(it * 2 + wn) * 256 + (jg * 16 + (t_) * 2 + wm)] = s_;   \
} while (0)

    {   // prologue: stage+normalize tile 0 into buf 0
        float4 fA[8], fB[8];
        SATLOAD(0, fA, fB);
        SATNORM(fA, wid*16 + rl16, 0);
        SATNORM(fB, 64 + wid*16 + rl16, 0);
        PUBLISH();
    }

    #pragma unroll 1
    for (int t = 0; t < 8; ++t) {
        f32x16 acc[2][2];
        #pragma unroll
        for (int m = 0; m < 2; ++m)
            #pragma unroll
            for (int n = 0; n < 2; ++n)
                #pragma unroll
                for (int q = 0; q < 16; ++q) acc[m][n][q] = 0.f;

        COMPUTE(t & 1, 0, 0);
        COMPUTE(t & 1, 1, 4);

        float4 fA[8], fB[8];
        const bool more = (t < 7);
        if (more) SATLOAD(t + 1, fA, fB);      // issue early: latency under epilogue

        EPILOGUE(t);

        if (more) {
            SATNORM(fA, wid*16 + rl16, (t + 1) & 1);
            SATNORM(fB, 64 + wid*16 + rl16, (t + 1) & 1);
            PUBLISH();
        }
    }

#undef SATLOAD
#undef SATNORM
#undef COMPUTE
#undef PUBLISH
#undef EPILOGUE
}

extern "C" void kernel_launch(void* const* d_in, const int* in_sizes, int n_in,
                              void* d_out, int out_size, void* d_ws, size_t ws_size,
                              hipStream_t stream) {
    const float* sat  = (const float*)d_in[0];   // [16384,128]
    const float* pano = (const float*)d_in[1];   // [ 4096,128]
    float* out = (float*)d_out;                  // [64,256]

    fused_maxsim<<<512, 256, 0, stream>>>(sat, pano, out);
}

// Round 9
// 38.307 us; speedup vs baseline: 2.9090x; 1.3798x over previous
//
#include <hip/hip_runtime.h>
#include <hip/hip_bf16.h>

// MEASUREMENT ROUND (passing config): R4's normalize+maxsim kept live;
// added pure-cast probe kernel x2 into a dead ws region.
//   D = 2*N(norm) + 2*C(cast) + 1*M(maxsim) + gaps
// Known family from R4/R5: N = 18.8-g, M = 11-g  ->  D ~ 48.6 + 2C + 2g.
// C fast (~4) => D ~ 56-63 (normalize STRUCTURE is the problem)
// C ~ N       => D ~ 82-92 (any streaming pass costs ~15us here)

typedef __bf16 bf16x8 __attribute__((ext_vector_type(8)));
typedef float  f32x16 __attribute__((ext_vector_type(16)));
typedef unsigned int u32;

__device__ __forceinline__ void gload16(const void* g, void* l) {
    __builtin_amdgcn_global_load_lds((const __attribute__((address_space(1))) u32*)g,
                                     (__attribute__((address_space(3))) u32*)l, 16, 0, 0);
}

__device__ __forceinline__ unsigned short f2bf_rne(float x) {
    u32 u = __builtin_bit_cast(u32, x);
    return (unsigned short)((u + 0x7FFFu + ((u >> 16) & 1u)) >> 16);
}

__device__ __forceinline__ u32 pkbf16(float a, float b) {
    u32 r;
    asm("v_cvt_pk_bf16_f32 %0, %1, %2" : "=v"(r) : "v"(a), "v"(b));
    return r;
}

// ---- probe: pure streaming cast fp32 -> bf16, no shfl, no div ----
// 655360 float4s total (sat 524288, pano 131072); 512x256 threads x 5 passes.
__global__ __launch_bounds__(256) void cast_probe(
        const float* __restrict__ sat, const float* __restrict__ pano,
        u32* __restrict__ dst) {
    int gtid = blockIdx.x * 256 + threadIdx.x;
    #pragma unroll
    for (int p = 0; p < 5; ++p) {
        int i = p * 131072 + gtid;
        const float4 v = (i < 524288)
            ? *reinterpret_cast<const float4*>(sat + (size_t)i * 4)
            : *reinterpret_cast<const float4*>(pano + (size_t)(i - 524288) * 4);
        uint2 o;
        o.x = pkbf16(v.x, v.y);
        o.y = pkbf16(v.z, v.w);
        *reinterpret_cast<uint2*>(dst + (size_t)i * 2) = o;
    }
}

// ---- R4 normalize (live) ----
__global__ __launch_bounds__(256) void normalize_all(
        const float* __restrict__ sat, const float* __restrict__ pano,
        unsigned short* __restrict__ satN, unsigned short* __restrict__ panoN) {
    int row  = blockIdx.x * 8 + (threadIdx.x >> 5);
    int lane = threadIdx.x & 31;
    const float* src;
    unsigned short* dst;
    if (row < 16384) { src = sat  + (size_t)row * 128;           dst = satN  + (size_t)row * 128; }
    else             { src = pano + (size_t)(row - 16384) * 128; dst = panoN + (size_t)(row - 16384) * 128; }
    const float4 v = *reinterpret_cast<const float4*>(src + lane * 4);
    float ss = v.x * v.x + v.y * v.y + v.z * v.z + v.w * v.w;
    #pragma unroll
    for (int m = 16; m >= 1; m >>= 1) ss += __shfl_xor(ss, m);
    float sc = 1.0f / fmaxf(sqrtf(ss), 1e-12f);
    ushort4 o;
    o.x = f2bf_rne(v.x * sc); o.y = f2bf_rne(v.y * sc);
    o.z = f2bf_rne(v.z * sc); o.w = f2bf_rne(v.w * sc);
    *reinterpret_cast<ushort4*>(dst + lane * 4) = o;
}

// ---- R4 maxsim (live, verified) ----
__global__ __launch_bounds__(256, 2) void maxsim_kernel(
        const unsigned short* __restrict__ satN,
        const unsigned short* __restrict__ panoN,
        float* __restrict__ out) {
    __shared__ unsigned short Slds[4][128 * 64];

    const int tid  = threadIdx.x;
    const int wid  = tid >> 6;
    const int lane = tid & 63;
    const int rl   = lane & 31;
    const int hi   = lane >> 5;

    const int bid = blockIdx.x;
    const int swz = (bid & 7) * 64 + (bid >> 3);
    const int jg  = swz >> 5;
    const int it  = swz & 31;

    const int wm = wid >> 1;
    const int wn = wid & 1;

    bf16x8 bfr[2][8];
    {
        const unsigned short* pb =
            panoN + ((size_t)(it * 128 + wn * 64 + rl)) * 128 + hi * 8;
        #pragma unroll
        for (int n = 0; n < 2; ++n)
            #pragma unroll
            for (int ks = 0; ks < 8; ++ks)
                bfr[n][ks] = *reinterpret_cast<const bf16x8*>(pb + (size_t)n * 32 * 128 + ks * 16);
    }

#define STAGE(h_) do {                                                          \
    const char* gb_ = (const char*)satN                                         \
        + ((size_t)(jg * 1024 + ((h_) >> 1) * 128)) * 256 + ((h_) & 1) * 128;   \
    char* lb_ = (char*)&Slds[(h_) & 3][0];                                      \
    _Pragma("unroll")                                                           \
    for (int i_ = 0; i_ < 4; ++i_) {                                            \
        int P_ = (wid * 4 + i_) * 1024 + lane * 16;                             \
        int r_ = P_ >> 7;                                                       \
        int g_ = ((P_ >> 4) & 7) ^ (r_ & 7);                                    \
        gload16(gb_ + (size_t)r_ * 256 + g_ * 16, lb_ + P_);                    \
    } } while (0)

#define COMPUTE(h_, koff_) do {                                                 \
    const char* sb_ = (const char*)&Slds[(h_) & 3][0];                          \
    __builtin_amdgcn_s_setprio(1);                                              \
    _Pragma("unroll")                                                           \
    for (int ks = 0; ks < 4; ++ks) {                                            \
        bf16x8 a_[2];                                                           \
        _Pragma("unroll")                                                       \
        for (int m = 0; m < 2; ++m) {                                           \
            int row = wm * 64 + m * 32 + rl;                                    \
            a_[m] = *(const bf16x8*)(sb_ + row * 128 + ((((ks << 1) | hi) ^ (row & 7)) << 4)); \
        }                                                                       \
        _Pragma("unroll")                                                       \
        for (int m = 0; m < 2; ++m)                                             \
            _Pragma("unroll")                                                   \
            for (int n = 0; n < 2; ++n)                                         \
                acc[m][n] = __builtin_amdgcn_mfma_f32_32x32x16_bf16(            \
                    a_[m], bfr[n][(koff_) + ks], acc[m][n], 0, 0, 0);           \
    }                                                                           \
    __builtin_amdgcn_s_setprio(0);                                              \
} while (0)

#define SYNC(N_) do {                                                           \
    asm volatile("s_waitcnt vmcnt(" #N_ ")" ::: "memory");                      \
    __builtin_amdgcn_s_barrier();                                               \
    __builtin_amdgcn_sched_barrier(0);                                          \
} while (0)

#define EPILOGUE(t_) do {                                                       \
    float v0 = acc[0][0][0], v1 = acc[0][1][0];                                 \
    _Pragma("unroll")                                                           \
    for (int m = 0; m < 2; ++m)                                                 \
        _Pragma("unroll")                                                       \
        for (int q = 0; q < 16; ++q) {                                          \
            if (m == 0 && q == 0) continue;                                     \
            v0 = fmaxf(v0, acc[m][0][q]);                                       \
            v1 = fmaxf(v1, acc[m][1][q]);                                       \
        }                                                                       \
    v0 = fmaxf(v0, __shfl_xor(v0, 32));                                         \
    v1 = fmaxf(v1, __shfl_xor(v1, 32));                                         \
    float s_ = v0 + v1;                                                         \
    _Pragma("unroll")                                                           \
    for (int d_ = 1; d_ <= 16; d_ <<= 1) s_ += __shfl_xor(s_, d_);              \
    if (lane == 0) out[(it * 2 + wn) * 256 + (jg * 16 + (t_) * 2 + wm)] = s_;   \
    _Pragma("unroll")                                                           \
    for (int m = 0; m < 2; ++m)                                                 \
        _Pragma("unroll")                                                       \
        for (int n = 0; n < 2; ++n)                                             \
            _Pragma("unroll")                                                   \
            for (int q = 0; q < 16; ++q) acc[m][n][q] = 0.f;                    \
} while (0)

    STAGE(0); STAGE(1); STAGE(2);

    f32x16 acc[2][2];
    #pragma unroll
    for (int m = 0; m < 2; ++m)
        #pragma unroll
        for (int n = 0; n < 2; ++n)
            #pragma unroll
            for (int q = 0; q < 16; ++q) acc[m][n][q] = 0.f;

    #pragma unroll 1
    for (int t = 0; t < 7; ++t) {
        const int h0 = 2 * t;
        SYNC(8);
        STAGE(h0 + 3);
        __builtin_amdgcn_sched_barrier(0);
        COMPUTE(h0, 0);

        SYNC(8);
        if (t < 6) STAGE(h0 + 4);
        __builtin_amdgcn_sched_barrier(0);
        COMPUTE(h0 + 1, 4);

        EPILOGUE(t);
    }
    SYNC(4);
    COMPUTE(14, 0);
    SYNC(0);
    COMPUTE(15, 4);
    EPILOGUE(7);

#undef STAGE
#undef COMPUTE
#undef SYNC
#undef EPILOGUE
}

extern "C" void kernel_launch(void* const* d_in, const int* in_sizes, int n_in,
                              void* d_out, int out_size, void* d_ws, size_t ws_size,
                              hipStream_t stream) {
    const float* sat  = (const float*)d_in[0];   // [16384,128]
    const float* pano = (const float*)d_in[1];   // [ 4096,128]
    float* out = (float*)d_out;                  // [64,256]

    unsigned short* panoN = (unsigned short*)d_ws;        // 4096*128 bf16
    unsigned short* satN  = panoN + (size_t)4096 * 128;   // 16384*128 bf16
    u32* deadCast = (u32*)((char*)d_ws + (32u << 20));    // dead probe region @ +32MB

    normalize_all<<<2560, 256, 0, stream>>>(sat, pano, satN, panoN);
    normalize_all<<<2560, 256, 0, stream>>>(sat, pano, satN, panoN);
    cast_probe<<<512, 256, 0, stream>>>(sat, pano, deadCast);
    cast_probe<<<512, 256, 0, stream>>>(sat, pano, deadCast);
    maxsim_kernel<<<512, 256, 0, stream>>>(satN, panoN, out);
}